// Round 7
// baseline (234.225 us; speedup 1.0000x reference)
//
#include <hip/hip_runtime.h>
#include <hip/hip_bf16.h>

// SpikingPolicyNet: B=8192, D_in=256, H=1024, D_out=64, T=15, TAU=20, V_TH=1
//
// Pipeline:
//  K0 : W2 -> W2cb (bf16 W2^T, signed) + W2p (relu'd bf16 W2^T + zero pad row)
//  K1 : bf16-MFMA x@W1.T; epilogue folds b1 and emits the closed-form spike
//       interval k = ceil(log2(1-1/I)/log2(0.95)) as a byte plane kb[b][j]
//       (layer-1 spikes at t = k,2k,...; I1 is time-invariant).
//  K2 : block-per-row. Ballot-built per-wave spiker lists (no atomics);
//       bound pass: U = b2 + sum_spikers relu(W2 col) >= max_t I2_t.
//       Induction v2_t <= U*(1-.95^t) < U, so U <= 0.999 (margin >> fp
//       drift) proves zero s2 spikes -> out = bout (bit-exact; absmax==0
//       in R1-R6). Gather is chunked 8-deep: 2 broadcast ds_read_b128 for
//       entries, then 8 independent coalesced dwordx2 loads in flight
//       (tail redirected to the zero pad row - no masking branches).
//       Rare rows run an exact per-step re-gather simulation.

#define B_SZ   8192
#define D_IN   256
#define H_SZ   1024
#define D_OUT  64
#define T_STEPS 15
#define SKIP_THR 0.999f
#define SEG    264            // per-wave list segment stride (256 max + pad)

typedef __attribute__((ext_vector_type(8))) short short8;
typedef __attribute__((ext_vector_type(4))) float f32x4;

static __device__ __forceinline__ unsigned int pk_bf16(float lo, float hi) {
    return (__builtin_bit_cast(unsigned int, hi) & 0xffff0000u) |
           (__builtin_bit_cast(unsigned int, lo) >> 16);
}

// packed bf16 pair -> two f32 adds into arr[u0], arr[u0+1] (exact unpack)
#define ADDPK(arr, w, u0)                                                     \
    { arr[(u0)]     += __builtin_bit_cast(float, (w) << 16);                  \
      arr[(u0) + 1] += __builtin_bit_cast(float, (w) & 0xffff0000u); }

// ---------------------------------------------------------------- K0: W2 -> W2cb + W2p(+pad)
__global__ __launch_bounds__(256) void k0_transpose(const float* __restrict__ W2,
                                                    unsigned short* __restrict__ W2cb,
                                                    unsigned short* __restrict__ W2p) {
    __shared__ float tile[32][33];
    const int bx = blockIdx.x * 32;
    const int by = blockIdx.y * 32;
    const int tx = threadIdx.x;
    const int ty = threadIdx.y;
    #pragma unroll
    for (int i = ty; i < 32; i += 8)
        tile[i][tx] = W2[(by + i) * H_SZ + bx + tx];
    __syncthreads();
    #pragma unroll
    for (int i = ty; i < 32; i += 8) {
        const unsigned int uv = __builtin_bit_cast(unsigned int, tile[tx][i]);
        const unsigned short bf = (unsigned short)(uv >> 16);
        const size_t idx = (size_t)(bx + i) * H_SZ + by + tx;
        W2cb[idx] = bf;
        W2p[idx]  = (bf & 0x8000u) ? (unsigned short)0 : bf;   // relu (exact on bf16)
    }
    if (blockIdx.x == 0 && blockIdx.y == 0) {                   // zero pad row 1024
        const int t = ty * 32 + tx;
        #pragma unroll
        for (int i = 0; i < 4; ++i)
            W2p[(size_t)H_SZ * H_SZ + i * 256 + t] = 0;
    }
}

// ---------------------------------------------------------------- K1: interval byte-plane from x@W1.T+b1
__global__ __launch_bounds__(256) void k1_mfma(const float* __restrict__ A,
                                               const float* __restrict__ Bw,
                                               const float* __restrict__ b1,
                                               unsigned char* __restrict__ kb) {
    __shared__ unsigned int As4[2048];   // 128 rows x 32 bf16, 16B-chunk XOR swizzle
    __shared__ unsigned int Bs4[2048];
    const int tid  = threadIdx.x;
    const int m0   = blockIdx.x * 128;
    const int n0   = blockIdx.y * 128;
    const int lane = tid & 63;
    const int wid  = tid >> 6;
    const int wr   = wid >> 1, wc = wid & 1;

    const int row0 = tid >> 2;
    const int row1 = row0 + 64;
    const int q0   = tid & 3;

    f32x4 acc[4][4] = {};
    float4 s0[8], s1[8];

    auto LOAD = [&](float4* s, int kbk) {
        const float* pa0 = A  + (m0 + row0) * D_IN + kbk + q0 * 8;
        const float* pa1 = A  + (m0 + row1) * D_IN + kbk + q0 * 8;
        const float* pb0 = Bw + (n0 + row0) * D_IN + kbk + q0 * 8;
        const float* pb1 = Bw + (n0 + row1) * D_IN + kbk + q0 * 8;
        s[0] = *(const float4*)pa0; s[1] = *(const float4*)(pa0 + 4);
        s[2] = *(const float4*)pa1; s[3] = *(const float4*)(pa1 + 4);
        s[4] = *(const float4*)pb0; s[5] = *(const float4*)(pb0 + 4);
        s[6] = *(const float4*)pb1; s[7] = *(const float4*)(pb1 + 4);
    };
    auto WRITE = [&](const float4* s) {
        const int i0 = row0 * 16 + (q0 ^ ((row0 >> 1) & 3)) * 4;
        const int i1 = row1 * 16 + (q0 ^ ((row1 >> 1) & 3)) * 4;
        *(uint4*)&As4[i0] = make_uint4(pk_bf16(s[0].x, s[0].y), pk_bf16(s[0].z, s[0].w),
                                       pk_bf16(s[1].x, s[1].y), pk_bf16(s[1].z, s[1].w));
        *(uint4*)&As4[i1] = make_uint4(pk_bf16(s[2].x, s[2].y), pk_bf16(s[2].z, s[2].w),
                                       pk_bf16(s[3].x, s[3].y), pk_bf16(s[3].z, s[3].w));
        *(uint4*)&Bs4[i0] = make_uint4(pk_bf16(s[4].x, s[4].y), pk_bf16(s[4].z, s[4].w),
                                       pk_bf16(s[5].x, s[5].y), pk_bf16(s[5].z, s[5].w));
        *(uint4*)&Bs4[i1] = make_uint4(pk_bf16(s[6].x, s[6].y), pk_bf16(s[6].z, s[6].w),
                                       pk_bf16(s[7].x, s[7].y), pk_bf16(s[7].z, s[7].w));
    };
    auto COMPUTE = [&]() {
        short8 afr[4], bfr[4];
        const int q  = lane >> 4;
        const int lr = lane & 15;
        #pragma unroll
        for (int mf = 0; mf < 4; ++mf) {
            const int ra = wr * 64 + mf * 16 + lr;
            afr[mf] = *(const short8*)&As4[ra * 16 + (q ^ ((ra >> 1) & 3)) * 4];
            const int rb = wc * 64 + mf * 16 + lr;
            bfr[mf] = *(const short8*)&Bs4[rb * 16 + (q ^ ((rb >> 1) & 3)) * 4];
        }
        #pragma unroll
        for (int mf = 0; mf < 4; ++mf)
            #pragma unroll
            for (int nf = 0; nf < 4; ++nf)
                acc[mf][nf] = __builtin_amdgcn_mfma_f32_16x16x32_bf16(
                    afr[mf], bfr[nf], acc[mf][nf], 0, 0, 0);
    };

    LOAD(s0, 0);
    for (int kk = 0; kk < D_IN; kk += 64) {
        if (kk + 32 < D_IN) LOAD(s1, kk + 32);
        __syncthreads();
        WRITE(s0);
        __syncthreads();
        COMPUTE();
        if (kk + 64 < D_IN) LOAD(s0, kk + 64);
        __syncthreads();
        WRITE(s1);
        __syncthreads();
        COMPUTE();
    }

    // Epilogue: I = acc + b1[col]; k = ceil(log2(1-1/I)*-13.5134035), 0 = none.
    // C/D layout (m89): col = lane&15, row = (lane>>4)*4 + r. Byte-plane store.
    const int lr = lane & 15;
    const int qq = lane >> 4;
    float b1v[4];
    #pragma unroll
    for (int nf = 0; nf < 4; ++nf) b1v[nf] = b1[n0 + wc * 64 + nf * 16 + lr];

    #pragma unroll
    for (int mf = 0; mf < 4; ++mf) {
        const int rbase = m0 + wr * 64 + mf * 16 + qq * 4;
        #pragma unroll
        for (int nf = 0; nf < 4; ++nf) {
            const int c = n0 + wc * 64 + nf * 16 + lr;
            #pragma unroll
            for (int r = 0; r < 4; ++r) {
                const float I = acc[mf][nf][r] + b1v[nf];
                int k = 0;
                if (I > 1.8632055f) {
                    const float l2 = __builtin_amdgcn_logf(1.0f - __builtin_amdgcn_rcpf(I));
                    int kc = (int)__builtin_ceilf(l2 * -13.5134035f);
                    k = kc < 1 ? 1 : (kc > 15 ? 15 : kc);
                }
                kb[(size_t)(rbase + r) * H_SZ + c] = (unsigned char)k;
            }
        }
    }
}

// ---------------------------------------------------------------- K2: block-per-row, deep-pipelined bound
__global__ __launch_bounds__(256, 8) void k2_snn(const unsigned char* __restrict__ kb,
                                                 const unsigned short* __restrict__ W2cb,
                                                 const unsigned short* __restrict__ W2p,
                                                 const float* __restrict__ b2,
                                                 const float* __restrict__ Wout,
                                                 const float* __restrict__ bout,
                                                 float* __restrict__ out) {
    const int b    = blockIdx.x;
    const int tid  = threadIdx.x;
    const int j0   = tid * 4;            // this thread's 4 neurons
    const int wid  = tid >> 6;
    const int lane = tid & 63;

    __shared__ unsigned int list[4 * SEG];   // per-wave segments: (j<<8)|k
    __shared__ int cnt_s[4];
    __shared__ unsigned int wneed_s[4];
    __shared__ float rrow[H_SZ];

    // ---- interval bytes for this thread's neurons (coalesced 4B/thread)
    const unsigned int kw = *(const unsigned int*)(kb + (size_t)b * H_SZ + j0);
    const float4 b2v = *(const float4*)&b2[j0];

    // ---- per-wave ballot-compacted spiker list (no atomics, no init barrier)
    {
        int base = wid * SEG;
        #pragma unroll
        for (int u = 0; u < 4; ++u) {
            const unsigned int ku = (kw >> (8 * u)) & 0xffu;
            const unsigned long long m = __ballot(ku != 0);
            if (ku) {
                const int pos = base + (int)__popcll(m & ((1ull << lane) - 1ull));
                list[pos] = ((unsigned int)(j0 + u) << 8) | ku;
            }
            base += (int)__popcll(m);
        }
        if (lane == 0) cnt_s[wid] = base - wid * SEG;
    }
    __syncthreads();                      // barrier #1: lists + counts visible

    const int nsA0 = cnt_s[0], nsA1 = cnt_s[1], nsA2 = cnt_s[2], nsA3 = cnt_s[3];

    // ---- bound pass: U = b2 + sum_spikers relu(W2 col), 8 loads in flight
    float U[4] = {b2v.x, b2v.y, b2v.z, b2v.w};
    auto BOUND = [&](int sb, int ns) {
        for (int s0 = 0; s0 < ns; s0 += 8) {
            const uint4 e0 = *(const uint4*)&list[sb + s0];       // broadcast reads
            const uint4 e1 = *(const uint4*)&list[sb + s0 + 4];
            const unsigned int ee[8] = {e0.x, e0.y, e0.z, e0.w,
                                        e1.x, e1.y, e1.z, e1.w};
            uint2 wv[8];
            #pragma unroll
            for (int i = 0; i < 8; ++i) {
                const int jj = (s0 + i < ns) ? (int)(ee[i] >> 8) : H_SZ; // pad->zero row
                wv[i] = *(const uint2*)(W2p + ((size_t)jj << 10) + j0);
            }
            #pragma unroll
            for (int i = 0; i < 8; ++i) { ADDPK(U, wv[i].x, 0) ADDPK(U, wv[i].y, 2) }
        }
    };
    BOUND(0 * SEG, nsA0); BOUND(1 * SEG, nsA1);
    BOUND(2 * SEG, nsA2); BOUND(3 * SEG, nsA3);

    const bool need = (U[0] > SKIP_THR) || (U[1] > SKIP_THR) ||
                      (U[2] > SKIP_THR) || (U[3] > SKIP_THR);
    const unsigned long long wb = __ballot(need);
    if (lane == 0) wneed_s[wid] = (wb != 0ull) ? 1u : 0u;
    __syncthreads();                      // barrier #2: need flags visible

    if ((wneed_s[0] | wneed_s[1] | wneed_s[2] | wneed_s[3]) == 0u) {
        // proven spike-free: out = bout (bit-exact)
        if (tid < D_OUT) out[(size_t)b * D_OUT + tid] = bout[tid];
        return;
    }

    // ---- rare exact path (block-uniform): per-step re-gather simulation
    float v20 = 0.f, v21 = 0.f, v22 = 0.f, v23 = 0.f;
    int c0 = 0, c1 = 0, c2 = 0, c3 = 0;
    for (int t = 1; t <= T_STEPS; ++t) {
        float i2[4] = {b2v.x, b2v.y, b2v.z, b2v.w};
        #pragma unroll
        for (int seg = 0; seg < 4; ++seg) {
            const int sb = seg * SEG;
            const int ns = (seg == 0) ? nsA0 : (seg == 1) ? nsA1
                         : (seg == 2) ? nsA2 : nsA3;
            for (int s = 0; s < ns; ++s) {
                const unsigned int e = list[sb + s];
                const unsigned int k = e & 0xffu;
                if ((t % (int)k) == 0) {
                    const int jj = (int)(e >> 8);
                    const uint2 w = *(const uint2*)(W2cb + ((size_t)jj << 10) + j0);
                    ADDPK(i2, w.x, 0) ADDPK(i2, w.y, 2)
                }
            }
        }
        v20 = fmaf(i2[0], 0.05f, v20 * 0.95f); if (v20 > 1.0f) { v20 = 0.f; ++c0; }
        v21 = fmaf(i2[1], 0.05f, v21 * 0.95f); if (v21 > 1.0f) { v21 = 0.f; ++c1; }
        v22 = fmaf(i2[2], 0.05f, v22 * 0.95f); if (v22 > 1.0f) { v22 = 0.f; ++c2; }
        v23 = fmaf(i2[3], 0.05f, v23 * 0.95f); if (v23 > 1.0f) { v23 = 0.f; ++c3; }
    }

    rrow[j0 + 0] = (float)c0 / 15.0f;
    rrow[j0 + 1] = (float)c1 / 15.0f;
    rrow[j0 + 2] = (float)c2 / 15.0f;
    rrow[j0 + 3] = (float)c3 / 15.0f;
    __syncthreads();
    if (tid < D_OUT) {
        float acc = bout[tid];
        const float* wr = Wout + (size_t)tid * H_SZ;
        for (int j = 0; j < H_SZ; ++j) acc = fmaf(rrow[j], wr[j], acc);
        out[(size_t)b * D_OUT + tid] = acc;
    }
}

// ---------------------------------------------------------------- launch
extern "C" void kernel_launch(void* const* d_in, const int* in_sizes, int n_in,
                              void* d_out, int out_size, void* d_ws, size_t ws_size,
                              hipStream_t stream) {
    const float* x    = (const float*)d_in[0];
    const float* W1   = (const float*)d_in[1];
    const float* b1   = (const float*)d_in[2];
    const float* W2   = (const float*)d_in[3];
    const float* b2   = (const float*)d_in[4];
    const float* Wout = (const float*)d_in[5];
    const float* bout = (const float*)d_in[6];
    float* out = (float*)d_out;

    char* ws = (char*)d_ws;
    unsigned short* W2cb = (unsigned short*)(ws);                 // 2 MB (signed)
    unsigned short* W2p  = (unsigned short*)(ws + (2 << 20));     // 2 MB + 2 KB pad row
    unsigned char*  kbuf = (unsigned char*)(ws + (8 << 20));      // 8 MB intervals

    k0_transpose<<<dim3(H_SZ / 32, H_SZ / 32), dim3(32, 8), 0, stream>>>(W2, W2cb, W2p);
    k1_mfma<<<dim3(B_SZ / 128, H_SZ / 128), 256, 0, stream>>>(x, W1, b1, kbuf);
    k2_snn<<<B_SZ, 256, 0, stream>>>(kbuf, W2cb, W2p, b2, Wout, bout, out);
}